// Round 13
// baseline (272.816 us; speedup 1.0000x reference)
//
#include <hip/hip_runtime.h>
#include <cstdint>

#define NNODES 8192
#define NEDGES 262144
#define NRELS  8
#define EMBD   256
#define BOXD   1024
#define HIDD   512
#define OUTD   256
#define NSEG   (NRELS * NNODES)      // 65536
#define K0DIM  (BOXD + EMBD)         // 1280
#define KSDIM  (NRELS * HIDD + HIDD) // 4608

// k_prep block-range boundaries
#define PREP_X0_END   8192
#define PREP_TR_END   (8192 + 2944)
#define PREP_WB_END   (8192 + 2944 + 18)
#define PREP_TOTAL    (8192 + 2944 + 18 + 1024)

#define PX_SPLITS 16

using bf16x8 = __attribute__((ext_vector_type(8))) short;
using f32x4  = __attribute__((ext_vector_type(4))) float;
using us4    = __attribute__((ext_vector_type(4))) unsigned short;

__device__ __forceinline__ unsigned short f2b(float f) {
    union { float f; uint32_t u; } v; v.f = f;
    uint32_t r = v.u + 0x7FFFu + ((v.u >> 16) & 1u);
    return (unsigned short)(r >> 16);
}

__device__ __forceinline__ us4 cvt4(f32x4 v) {
    us4 u;
    u[0] = f2b(v[0]); u[1] = f2b(v[1]); u[2] = f2b(v[2]); u[3] = f2b(v[3]);
    return u;
}

__device__ __forceinline__ float b2f_lo(uint32_t w) {
    union { uint32_t u; float f; } v; v.u = w << 16; return v.f;
}
__device__ __forceinline__ float b2f_hi(uint32_t w) {
    union { uint32_t u; float f; } v; v.u = w & 0xffff0000u; return v.f;
}

// ---------------------------------------------------------------------------
// Fused prep: build_x0 | weight transposes | head-weight fold | edge histogram.
// ---------------------------------------------------------------------------
__global__ __launch_bounds__(256) void k_prep(
        const float* __restrict__ box, const int* __restrict__ labels,
        const float* __restrict__ emb,
        const float* __restrict__ W_lin, const float* __restrict__ rel_W1,
        const float* __restrict__ root_W1, const float* __restrict__ rel_W2,
        const float* __restrict__ root_W2,
        const float* __restrict__ Wc1, const float* __restrict__ bc1,
        const float* __restrict__ Wc2, const float* __restrict__ bc2,
        const float* __restrict__ b2,
        const int* __restrict__ etype, const int* __restrict__ edst,
        unsigned short* __restrict__ X0, unsigned short* __restrict__ W0t,
        unsigned short* __restrict__ W1t, float* __restrict__ Wbig,
        float* __restrict__ bbig, int* __restrict__ cnt) {
    int bid = blockIdx.x;
    if (bid < PREP_X0_END) {
        int n = bid;
        int lab = labels[n];
        const f32x4* b = (const f32x4*)(box + (size_t)n * BOXD);
        const f32x4* e = (const f32x4*)(emb + (size_t)lab * EMBD);
        us4* o = (us4*)(X0 + (size_t)n * K0DIM);
        for (int j = threadIdx.x; j < K0DIM / 4; j += 256) {
            f32x4 v = (j < BOXD / 4) ? b[j] : e[j - BOXD / 4];
            o[j] = cvt4(v);
        }
    } else if (bid < PREP_TR_END) {
        __shared__ float t[32][33];
        int lb = bid - PREP_X0_END;
        const float* src; unsigned short* dst; int No, ld, kOff, kb, ob;
        if (lb < 640)       { int g = lb;        src = W_lin;   dst = W0t; No = 512; ld = K0DIM; kOff = 0;    kb = g % 40;  ob = g / 40; }
        else if (lb < 2688) { int g = lb - 640;  src = rel_W1;  dst = W1t; No = 512; ld = KSDIM; kOff = 0;    kb = g % 128; ob = g / 128; }
        else                { int g = lb - 2688; src = root_W1; dst = W1t; No = 512; ld = KSDIM; kOff = 4096; kb = g % 16;  ob = g / 16; }
        int kt = kb * 32, ot = ob * 32;
        int tx = threadIdx.x & 31, ty = threadIdx.x >> 5; // 32 x 8
#pragma unroll
        for (int i = 0; i < 4; i++) {
            int k = kt + ty + i * 8;
            t[ty + i * 8][tx] = src[(size_t)k * No + ot + tx];
        }
        __syncthreads();
#pragma unroll
        for (int i = 0; i < 4; i++) {
            int o = ot + ty + i * 8;
            dst[(size_t)o * ld + kOff + kt + tx] = f2b(t[tx][ty + i * 8]);
        }
    } else if (bid < PREP_WB_END) {
        __shared__ float ws0[256], ws1[256];
        __shared__ float r0[256], r1[256];
        int g = bid - PREP_TR_END;   // 0..17
        int i = threadIdx.x;
        float w0 = 0.f, w1 = 0.f;
        for (int o = 0; o < 256; o++) {
            float c = Wc1[i * 256 + o];
            w0 += c * Wc2[o * 2 + 0];
            w1 += c * Wc2[o * 2 + 1];
        }
        ws0[i] = w0; ws1[i] = w1;
        __syncthreads();
        int k = g * 256 + i;
        const float* row = (k < 4096) ? rel_W2 + (size_t)k * 256
                                      : root_W2 + (size_t)(k - 4096) * 256;
        float s0 = 0.f, s1 = 0.f;
        for (int o = 0; o < 256; o++) {
            float v = row[o];
            s0 += v * ws0[o];
            s1 += v * ws1[o];
        }
        Wbig[k * 2 + 0] = s0;
        Wbig[k * 2 + 1] = s1;
        if (g == 0) {
            r0[i] = b2[i] * ws0[i] + bc1[i] * Wc2[i * 2 + 0];
            r1[i] = b2[i] * ws1[i] + bc1[i] * Wc2[i * 2 + 1];
            __syncthreads();
            for (int s = 128; s > 0; s >>= 1) {
                if (i < s) { r0[i] += r0[i + s]; r1[i] += r1[i + s]; }
                __syncthreads();
            }
            if (i == 0) { bbig[0] = r0[0] + bc2[0]; bbig[1] = r1[0] + bc2[1]; }
        }
    } else {
        int e = (bid - PREP_WB_END) * 256 + threadIdx.x;
        atomicAdd(&cnt[etype[e] * NNODES + edst[e]], 1);
    }
}

// ---------------------------------------------------------------------------
// 1024-thread two-level exclusive scan of cnt[65536] -> segstart[65537]
// ---------------------------------------------------------------------------
__global__ __launch_bounds__(1024) void k_scan(const int* __restrict__ cnt,
                                               int* __restrict__ segstart) {
    __shared__ int part[1024];
    __shared__ int sup[16];
    __shared__ int supx[16];
    int t = threadIdx.x;
    int base = t * 64;
    int s = 0;
    for (int i = 0; i < 64; i++) s += cnt[base + i];
    part[t] = s;
    __syncthreads();
    if (t < 16) {
        int a = 0;
        for (int i = 0; i < 64; i++) a += part[t * 64 + i];
        sup[t] = a;
    }
    __syncthreads();
    if (t == 0) {
        int a = 0;
        for (int i = 0; i < 16; i++) { supx[i] = a; a += sup[i]; }
    }
    __syncthreads();
    int a = supx[t >> 6];
    for (int i = (t & ~63); i < t; i++) a += part[i];
    for (int i = 0; i < 64; i++) { segstart[base + i] = a; a += cnt[base + i]; }
    if (t == 1023) segstart[NSEG] = a;
}

// ---------------------------------------------------------------------------
// Scatter (CSR sort) + layer-2 coefficient build:
// Cf[(r*64+g)][src] += 1/(128*cnt(seg)) for each edge (empty segs: no edges).
// ---------------------------------------------------------------------------
__global__ void k_scatter(const int* __restrict__ etype, const int* __restrict__ esrc,
                          const int* __restrict__ edst, const int* __restrict__ segstart,
                          int* __restrict__ cursor, int* __restrict__ esorted,
                          float* __restrict__ Cf) {
    int e = blockIdx.x * 256 + threadIdx.x;
    if (e >= NEDGES) return;
    int r = etype[e], d = edst[e], s = esrc[e];
    int key = r * NNODES + d;
    int pos = atomicAdd(&cursor[key], 1);
    esorted[segstart[key] + pos] = s;
    int cntv = segstart[key + 1] - segstart[key];
    float w = 1.0f / (128.0f * (float)cntv);
    atomicAdd(&Cf[(size_t)(r * 64 + (d >> 7)) * NNODES + s], w);
}

// Convert Cf fp32 [512][8192] -> Cbf bf16 (Cf aliases Pp; must run pre-GEMM0)
__global__ void k_c2bf(const float* __restrict__ Cf, unsigned short* __restrict__ Cbf) {
    int idx = (blockIdx.x * 256 + threadIdx.x) * 4;
    f32x4 v = *(const f32x4*)&Cf[idx];
    *(us4*)&Cbf[idx] = cvt4(v);
}

// ---------------------------------------------------------------------------
// Layer-1 aggregation (R8 measured form): one wave per (rel,dst) segment.
// ---------------------------------------------------------------------------
__global__ __launch_bounds__(256) void k_aggregate(
        const unsigned short* __restrict__ x, const int* __restrict__ segstart,
        const int* __restrict__ esorted, unsigned short* __restrict__ Xin) {
    int seg = blockIdx.x * 4 + (threadIdx.x >> 6);
    int lane = threadIdx.x & 63;
    int r = seg >> 13;
    int dstn = seg & (NNODES - 1);
    float a[8] = {0, 0, 0, 0, 0, 0, 0, 0};
    float b[8] = {0, 0, 0, 0, 0, 0, 0, 0};
    int s0 = segstart[seg], s1 = segstart[seg + 1];
    int t = s0;
    for (; t + 2 <= s1; t += 2) {
        uint4 v0 = *(const uint4*)(x + (size_t)esorted[t] * HIDD + lane * 8);
        uint4 v1 = *(const uint4*)(x + (size_t)esorted[t + 1] * HIDD + lane * 8);
        a[0] += b2f_lo(v0.x); a[1] += b2f_hi(v0.x);
        a[2] += b2f_lo(v0.y); a[3] += b2f_hi(v0.y);
        a[4] += b2f_lo(v0.z); a[5] += b2f_hi(v0.z);
        a[6] += b2f_lo(v0.w); a[7] += b2f_hi(v0.w);
        b[0] += b2f_lo(v1.x); b[1] += b2f_hi(v1.x);
        b[2] += b2f_lo(v1.y); b[3] += b2f_hi(v1.y);
        b[4] += b2f_lo(v1.z); b[5] += b2f_hi(v1.z);
        b[6] += b2f_lo(v1.w); b[7] += b2f_hi(v1.w);
    }
    if (t < s1) {
        uint4 v0 = *(const uint4*)(x + (size_t)esorted[t] * HIDD + lane * 8);
        a[0] += b2f_lo(v0.x); a[1] += b2f_hi(v0.x);
        a[2] += b2f_lo(v0.y); a[3] += b2f_hi(v0.y);
        a[4] += b2f_lo(v0.z); a[5] += b2f_hi(v0.z);
        a[6] += b2f_lo(v0.w); a[7] += b2f_hi(v0.w);
    }
    float iv = (s1 > s0) ? (1.0f / (float)(s1 - s0)) : 1.0f;
#pragma unroll
    for (int j = 0; j < 8; j++) a[j] = (a[j] + b[j]) * iv;
    uint4 u;
    u.x = (uint32_t)f2b(a[0]) | ((uint32_t)f2b(a[1]) << 16);
    u.y = (uint32_t)f2b(a[2]) | ((uint32_t)f2b(a[3]) << 16);
    u.z = (uint32_t)f2b(a[4]) | ((uint32_t)f2b(a[5]) << 16);
    u.w = (uint32_t)f2b(a[6]) | ((uint32_t)f2b(a[7]) << 16);
    *(uint4*)(Xin + (size_t)dstn * KSDIM + r * HIDD + lane * 8) = u;
}

// ---------------------------------------------------------------------------
// Transpose xbf [8192][512] -> xT [512][8192] (bf16, LDS-tiled).
// ---------------------------------------------------------------------------
__global__ void k_xT(const unsigned short* __restrict__ xbf, unsigned short* __restrict__ xT) {
    __shared__ unsigned short t[32][33];
    int b = blockIdx.x;
    int rt = (b & 255) * 32, ct = (b >> 8) * 32;
    int tx = threadIdx.x & 31, ty = threadIdx.x >> 5;  // 32 x 8
#pragma unroll
    for (int i = 0; i < 4; i++)
        t[ty + i * 8][tx] = xbf[(size_t)(rt + ty + i * 8) * HIDD + ct + tx];
    __syncthreads();
#pragma unroll
    for (int i = 0; i < 4; i++)
        xT[(size_t)(ct + ty + i * 8) * NNODES + rt + tx] = t[tx][ty + i * 8];
}

// ---------------------------------------------------------------------------
// bf16 MFMA GEMM, split-K partials. 128x128 tile, BK=64, 8 waves (2x4),
// XOR swizzle slot = chunk ^ (row&7), double-buffered, one drain per K-tile.
// (R3 measured config: 47.7us, MfmaUtil 32%, 2 blocks/CU — empirical best)
// ---------------------------------------------------------------------------
__global__ __launch_bounds__(512, 4) void k_gemm(
        const unsigned short* __restrict__ A,   // [M][K] bf16
        const unsigned short* __restrict__ Bt,  // [N][K] bf16
        float* __restrict__ P,                  // [S][M][N] partials
        int M, int N, int K, int Kc) {
    __shared__ unsigned short As[2][128 * 64];
    __shared__ unsigned short Bs[2][128 * 64];
    const int tid = threadIdx.x;
    const int lane = tid & 63, wid = tid >> 6;
    const int tiles_m = M >> 7;
    const int tm = blockIdx.x % tiles_m, tn = blockIdx.x / tiles_m;
    const int m0 = tm << 7, n0 = tn << 7;
    const int wr = wid >> 2, wc = wid & 3;       // 2 x 4 wave grid
    const int k0 = blockIdx.y * Kc;

    f32x4 acc[4][2];
#pragma unroll
    for (int i = 0; i < 4; i++)
#pragma unroll
        for (int j = 0; j < 2; j++) acc[i][j] = (f32x4){0.f, 0.f, 0.f, 0.f};

    const int rowg = tid >> 3;
    const int srcc = (tid & 7) ^ (rowg & 7);
    const unsigned short* gA = A  + (size_t)(m0 + rowg) * K + k0 + srcc * 8;
    const unsigned short* gB = Bt + (size_t)(n0 + rowg) * K + k0 + srcc * 8;
    const int ldsbase = wid * 512;

    auto stage = [&](int bsel, int kt) {
#pragma unroll
        for (int i = 0; i < 2; ++i) {
            __builtin_amdgcn_global_load_lds(
                (const __attribute__((address_space(1))) void*)(gA + kt + i * 64 * K),
                (__attribute__((address_space(3))) void*)&As[bsel][i * 4096 + ldsbase], 16, 0, 0);
            __builtin_amdgcn_global_load_lds(
                (const __attribute__((address_space(1))) void*)(gB + kt + i * 64 * K),
                (__attribute__((address_space(3))) void*)&Bs[bsel][i * 4096 + ldsbase], 16, 0, 0);
        }
    };

    const int arow = wr * 64 + (lane & 15);
    const int brow = wc * 32 + (lane & 15);
    const int l7 = lane & 7;
    const int c0 = lane >> 4;   // 0..3

    const int nt = Kc >> 6;
    int cur = 0;
    stage(0, 0);
    asm volatile("s_waitcnt vmcnt(0)" ::: "memory");
    __builtin_amdgcn_s_barrier();

    for (int t = 0; t < nt; ++t) {
        if (t + 1 < nt) stage(cur ^ 1, (t + 1) * 64);
#pragma unroll
        for (int s4 = 0; s4 < 2; ++s4) {
            const int slot = (c0 + s4 * 4) ^ l7;
            bf16x8 af[4], bfr[2];
#pragma unroll
            for (int m = 0; m < 4; m++)
                af[m] = *(const bf16x8*)&As[cur][(arow + m * 16) * 64 + slot * 8];
#pragma unroll
            for (int n = 0; n < 2; n++)
                bfr[n] = *(const bf16x8*)&Bs[cur][(brow + n * 16) * 64 + slot * 8];
#pragma unroll
            for (int m = 0; m < 4; m++)
#pragma unroll
                for (int n = 0; n < 2; n++)
                    acc[m][n] = __builtin_amdgcn_mfma_f32_16x16x32_bf16(af[m], bfr[n], acc[m][n], 0, 0, 0);
        }
        if (t + 1 < nt) {
            asm volatile("s_waitcnt vmcnt(0)" ::: "memory");
            __builtin_amdgcn_s_barrier();
            cur ^= 1;
        }
    }

    float* Pout = P + (size_t)blockIdx.y * M * N;
    const int crow0 = m0 + wr * 64 + (lane >> 4) * 4;
    const int ccol0 = n0 + wc * 32 + (lane & 15);
#pragma unroll
    for (int n = 0; n < 2; n++) {
        int col = ccol0 + n * 16;
#pragma unroll
        for (int m = 0; m < 4; m++)
#pragma unroll
            for (int r = 0; r < 4; r++)
                Pout[(size_t)(crow0 + m * 16 + r) * N + col] = acc[m][n][r];
    }
}

// ---------------------------------------------------------------------------
// Reduce S=2 partials + bias (+ReLU) -> bf16 x (optionally + Xin root cols)
// ---------------------------------------------------------------------------
template <int RELU, int WROOT>
__global__ void k_reduce_bf(const float* __restrict__ P, const float* __restrict__ bias,
                            unsigned short* __restrict__ xbf, unsigned short* __restrict__ Xin,
                            int MN) {
    int idx = (blockIdx.x * 256 + threadIdx.x) * 4;
    f32x4 v = *(const f32x4*)&P[idx];
    v += *(const f32x4*)&P[(size_t)MN + idx];
    v += *(const f32x4*)&bias[idx & 511];
    if (RELU) {
#pragma unroll
        for (int j = 0; j < 4; j++) v[j] = fmaxf(v[j], 0.f);
    }
    us4 u = cvt4(v);
    *(us4*)&xbf[idx] = u;
    if (WROOT) {
        int row = idx >> 9, col = idx & 511;
        *(us4*)&Xin[(size_t)row * KSDIM + NRELS * HIDD + col] = u;
    }
}

// ---------------------------------------------------------------------------
// Final head. Block g:
//   rel part: PX[(r*64+g)][c] = sum_s P[s] (PX split-K partials), dot Wbig
//   root part: (1/128) sum_{n in g} x2[n] . Wbig[4096:]  (read from xbf)
// ---------------------------------------------------------------------------
__global__ __launch_bounds__(256) void k_logits(
        const float* __restrict__ P, const unsigned short* __restrict__ xbf,
        const float* __restrict__ Wbig, const float* __restrict__ bbig,
        float* __restrict__ out) {
    __shared__ float r0[256], r1[256];
    __shared__ float wr0[512], wr1[512];
    int g = blockIdx.x, tid = threadIdx.x;
    for (int c = tid; c < 512; c += 256) {
        wr0[c] = Wbig[(4096 + c) * 2 + 0];
        wr1[c] = Wbig[(4096 + c) * 2 + 1];
    }
    float s0 = 0.f, s1 = 0.f;
#pragma unroll
    for (int r = 0; r < 8; r++) {
        const float* pr = P + (size_t)(r * 64 + g) * 512;
        for (int c = tid; c < 512; c += 256) {
            float px = 0.f;
#pragma unroll
            for (int s = 0; s < PX_SPLITS; s++) px += pr[(size_t)s * 512 * 512 + c];
            s0 += px * Wbig[(r * 512 + c) * 2 + 0];
            s1 += px * Wbig[(r * 512 + c) * 2 + 1];
        }
    }
    __syncthreads();
    // root: thread covers row n = g*128 + tid/2, cols [(tid&1)*256, +256)
    int n = g * 128 + (tid >> 1);
    int cbase = (tid & 1) * 256;
    const unsigned short* xr = xbf + (size_t)n * HIDD + cbase;
    float t0 = 0.f, t1 = 0.f;
    for (int c = 0; c < 256; c += 8) {
        uint4 v = *(const uint4*)(xr + c);
        float x0 = b2f_lo(v.x), x1 = b2f_hi(v.x);
        float x2 = b2f_lo(v.y), x3 = b2f_hi(v.y);
        float x4 = b2f_lo(v.z), x5 = b2f_hi(v.z);
        float x6 = b2f_lo(v.w), x7 = b2f_hi(v.w);
        int cc = cbase + c;
        t0 += x0 * wr0[cc] + x1 * wr0[cc + 1] + x2 * wr0[cc + 2] + x3 * wr0[cc + 3]
            + x4 * wr0[cc + 4] + x5 * wr0[cc + 5] + x6 * wr0[cc + 6] + x7 * wr0[cc + 7];
        t1 += x0 * wr1[cc] + x1 * wr1[cc + 1] + x2 * wr1[cc + 2] + x3 * wr1[cc + 3]
            + x4 * wr1[cc + 4] + x5 * wr1[cc + 5] + x6 * wr1[cc + 6] + x7 * wr1[cc + 7];
    }
    s0 += t0 * (1.0f / 128.0f);
    s1 += t1 * (1.0f / 128.0f);
    r0[tid] = s0; r1[tid] = s1;
    __syncthreads();
    for (int s = 128; s > 0; s >>= 1) {
        if (tid < s) { r0[tid] += r0[tid + s]; r1[tid] += r1[tid + s]; }
        __syncthreads();
    }
    if (tid == 0) {
        float l0 = r0[0] + bbig[0], l1 = r1[0] + bbig[1];
        out[g * 2 + 0] = l0;
        out[g * 2 + 1] = l1;
        float m = fmaxf(l0, l1);
        float e0 = expf(l0 - m), e1 = expf(l1 - m);
        float inv = 1.0f / (e0 + e1);
        out[128 + g * 2 + 0] = e0 * inv;
        out[128 + g * 2 + 1] = e1 * inv;
    }
}

// ---------------------------------------------------------------------------
extern "C" void kernel_launch(void* const* d_in, const int* in_sizes, int n_in,
                              void* d_out, int out_size, void* d_ws, size_t ws_size,
                              hipStream_t stream) {
    const float* box     = (const float*)d_in[0];
    const int*   labels  = (const int*)d_in[1];
    const int*   eidx    = (const int*)d_in[2];
    const int*   etype   = (const int*)d_in[3];
    const float* emb     = (const float*)d_in[5];
    const float* W_lin   = (const float*)d_in[6];
    const float* b_lin   = (const float*)d_in[7];
    const float* rel_W1  = (const float*)d_in[8];
    const float* root_W1 = (const float*)d_in[9];
    const float* b1      = (const float*)d_in[10];
    const float* rel_W2  = (const float*)d_in[11];
    const float* root_W2 = (const float*)d_in[12];
    const float* b2      = (const float*)d_in[13];
    const float* Wc1     = (const float*)d_in[14];
    const float* bc1     = (const float*)d_in[15];
    const float* Wc2     = (const float*)d_in[16];
    const float* bc2     = (const float*)d_in[17];
    const int* esrc = eidx;
    const int* edst = eidx + NEDGES;

    char* ws = (char*)d_ws;
    size_t off = 0;
    auto alloc = [&](size_t bytes) -> char* {
        char* p = ws + off;
        off += (bytes + 255) & ~(size_t)255;
        return p;
    };
    float* Pp = (float*)alloc((size_t)2 * NNODES * HIDD * 4);   // 32 MB
    float* Cf = Pp;  // fp32 coef matrix [512][8192] (16 MB) — dead before GEMM0 writes Pp
    unsigned short* Xin = (unsigned short*)alloc((size_t)NNODES * KSDIM * 2);  // 75.5 MB
    unsigned short* X0  = Xin;                 // dead after L0 GEMM
    unsigned short* xT  = (unsigned short*)Xin; // [512][8192] bf16 (8 MB) — Xin dead after L1 GEMM
    unsigned short* xbf = (unsigned short*)alloc((size_t)NNODES * HIDD * 2);
    unsigned short* W0t = (unsigned short*)alloc((size_t)HIDD * K0DIM * 2);
    unsigned short* W1t = (unsigned short*)alloc((size_t)HIDD * KSDIM * 2);
    unsigned short* Cbf = (unsigned short*)alloc((size_t)512 * NNODES * 2);  // 8 MB
    float* Wbig   = (float*)alloc((size_t)KSDIM * 2 * 4);
    float* bbig   = (float*)alloc(2 * 4);
    int*   cnt     = (int*)alloc((size_t)NSEG * 4);
    int*   cursor  = (int*)alloc((size_t)NSEG * 4);   // contiguous with cnt
    int*   segst   = (int*)alloc((size_t)(NSEG + 1) * 4);
    int*   esorted = (int*)alloc((size_t)NEDGES * 4);
    if (off > ws_size) return;

    float* out = (float*)d_out;
    const int MN = NNODES * HIDD;

    // --- prep: memsets + fused {build_x0 | transposes | head-fold | hist} ---
    hipMemsetAsync(cnt, 0, (size_t)2 * NSEG * 4, stream);   // cnt + cursor
    hipMemsetAsync(Cf, 0, (size_t)512 * NNODES * 4, stream);
    k_prep<<<PREP_TOTAL, 256, 0, stream>>>(
        box, labels, emb, W_lin, rel_W1, root_W1, rel_W2, root_W2,
        Wc1, bc1, Wc2, bc2, b2, etype, edst,
        X0, W0t, W1t, Wbig, bbig, cnt);
    k_scan<<<1, 1024, 0, stream>>>(cnt, segst);
    k_scatter<<<NEDGES / 256, 256, 0, stream>>>(etype, esrc, edst, segst, cursor, esorted, Cf);
    k_c2bf<<<512 * NNODES / 1024, 256, 0, stream>>>(Cf, Cbf);  // before GEMM0 (Cf aliases Pp)

    // --- layer 0: x1 = X0 @ W_lin + b_lin  (S=2, Kc=640) ---
    k_gemm<<<dim3((NNODES / 128) * (HIDD / 128), 2), 512, 0, stream>>>(
        X0, W0t, Pp, NNODES, HIDD, K0DIM, K0DIM / 2);
    k_reduce_bf<0, 1><<<MN / 1024, 256, 0, stream>>>(Pp, b_lin, xbf, Xin, MN);

    // --- RGCN layer 1: x2 = relu([A(x1) | x1] @ [rel_W1; root_W1] + b1)  (S=2) ---
    k_aggregate<<<NSEG / 4, 256, 0, stream>>>(xbf, segst, esorted, Xin);
    k_gemm<<<dim3((NNODES / 128) * (HIDD / 128), 2), 512, 0, stream>>>(
        Xin, W1t, Pp, NNODES, HIDD, KSDIM, KSDIM / 2);
    k_reduce_bf<1, 0><<<MN / 1024, 256, 0, stream>>>(Pp, b1, xbf, Xin, MN);

    // --- layer 2 + pool as GEMM: PX = Cbf @ x2  (x2 via transpose), then head ---
    k_xT<<<4096, 256, 0, stream>>>(xbf, xT);
    k_gemm<<<dim3((512 / 128) * (512 / 128), PX_SPLITS), 512, 0, stream>>>(
        Cbf, xT, Pp, 512, 512, NNODES, NNODES / PX_SPLITS);
    k_logits<<<64, 256, 0, stream>>>(Pp, xbf, Wbig, bbig, out);
}

// Round 14
// 257.312 us; speedup vs baseline: 1.0603x; 1.0603x over previous
//
#include <hip/hip_runtime.h>
#include <cstdint>

#define NNODES 8192
#define NEDGES 262144
#define NRELS  8
#define EMBD   256
#define BOXD   1024
#define HIDD   512
#define OUTD   256
#define NSEG   (NRELS * NNODES)      // 65536
#define K0DIM  (BOXD + EMBD)         // 1280
#define KSDIM  (NRELS * HIDD + HIDD) // 4608

// k_prep block-range boundaries
#define PREP_X0_END   8192
#define PREP_TR_END   (8192 + 2944)
#define PREP_WB_END   (8192 + 2944 + 18)
#define PREP_TOTAL    (8192 + 2944 + 18 + 1024)

using bf16x8 = __attribute__((ext_vector_type(8))) short;
using f32x4  = __attribute__((ext_vector_type(4))) float;
using us4    = __attribute__((ext_vector_type(4))) unsigned short;

__device__ __forceinline__ unsigned short f2b(float f) {
    union { float f; uint32_t u; } v; v.f = f;
    uint32_t r = v.u + 0x7FFFu + ((v.u >> 16) & 1u);
    return (unsigned short)(r >> 16);
}

__device__ __forceinline__ us4 cvt4(f32x4 v) {
    us4 u;
    u[0] = f2b(v[0]); u[1] = f2b(v[1]); u[2] = f2b(v[2]); u[3] = f2b(v[3]);
    return u;
}

__device__ __forceinline__ float b2f_lo(uint32_t w) {
    union { uint32_t u; float f; } v; v.u = w << 16; return v.f;
}
__device__ __forceinline__ float b2f_hi(uint32_t w) {
    union { uint32_t u; float f; } v; v.u = w & 0xffff0000u; return v.f;
}

// ---------------------------------------------------------------------------
// Fused prep: build_x0 | weight transposes | head-weight fold | edge histogram.
// ---------------------------------------------------------------------------
__global__ __launch_bounds__(256) void k_prep(
        const float* __restrict__ box, const int* __restrict__ labels,
        const float* __restrict__ emb,
        const float* __restrict__ W_lin, const float* __restrict__ rel_W1,
        const float* __restrict__ root_W1, const float* __restrict__ rel_W2,
        const float* __restrict__ root_W2,
        const float* __restrict__ Wc1, const float* __restrict__ bc1,
        const float* __restrict__ Wc2, const float* __restrict__ bc2,
        const float* __restrict__ b2,
        const int* __restrict__ etype, const int* __restrict__ edst,
        unsigned short* __restrict__ X0, unsigned short* __restrict__ W0t,
        unsigned short* __restrict__ W1t, float* __restrict__ Wbig,
        float* __restrict__ bbig, int* __restrict__ cnt) {
    int bid = blockIdx.x;
    if (bid < PREP_X0_END) {
        int n = bid;
        int lab = labels[n];
        const f32x4* b = (const f32x4*)(box + (size_t)n * BOXD);
        const f32x4* e = (const f32x4*)(emb + (size_t)lab * EMBD);
        us4* o = (us4*)(X0 + (size_t)n * K0DIM);
        for (int j = threadIdx.x; j < K0DIM / 4; j += 256) {
            f32x4 v = (j < BOXD / 4) ? b[j] : e[j - BOXD / 4];
            o[j] = cvt4(v);
        }
    } else if (bid < PREP_TR_END) {
        __shared__ float t[32][33];
        int lb = bid - PREP_X0_END;
        const float* src; unsigned short* dst; int No, ld, kOff, kb, ob;
        if (lb < 640)       { int g = lb;        src = W_lin;   dst = W0t; No = 512; ld = K0DIM; kOff = 0;    kb = g % 40;  ob = g / 40; }
        else if (lb < 2688) { int g = lb - 640;  src = rel_W1;  dst = W1t; No = 512; ld = KSDIM; kOff = 0;    kb = g % 128; ob = g / 128; }
        else                { int g = lb - 2688; src = root_W1; dst = W1t; No = 512; ld = KSDIM; kOff = 4096; kb = g % 16;  ob = g / 16; }
        int kt = kb * 32, ot = ob * 32;
        int tx = threadIdx.x & 31, ty = threadIdx.x >> 5; // 32 x 8
#pragma unroll
        for (int i = 0; i < 4; i++) {
            int k = kt + ty + i * 8;
            t[ty + i * 8][tx] = src[(size_t)k * No + ot + tx];
        }
        __syncthreads();
#pragma unroll
        for (int i = 0; i < 4; i++) {
            int o = ot + ty + i * 8;
            dst[(size_t)o * ld + kOff + kt + tx] = f2b(t[tx][ty + i * 8]);
        }
    } else if (bid < PREP_WB_END) {
        __shared__ float ws0[256], ws1[256];
        __shared__ float r0[256], r1[256];
        int g = bid - PREP_TR_END;   // 0..17
        int i = threadIdx.x;
        float w0 = 0.f, w1 = 0.f;
        for (int o = 0; o < 256; o++) {
            float c = Wc1[i * 256 + o];
            w0 += c * Wc2[o * 2 + 0];
            w1 += c * Wc2[o * 2 + 1];
        }
        ws0[i] = w0; ws1[i] = w1;
        __syncthreads();
        int k = g * 256 + i;
        const float* row = (k < 4096) ? rel_W2 + (size_t)k * 256
                                      : root_W2 + (size_t)(k - 4096) * 256;
        float s0 = 0.f, s1 = 0.f;
        for (int o = 0; o < 256; o++) {
            float v = row[o];
            s0 += v * ws0[o];
            s1 += v * ws1[o];
        }
        Wbig[k * 2 + 0] = s0;
        Wbig[k * 2 + 1] = s1;
        if (g == 0) {
            r0[i] = b2[i] * ws0[i] + bc1[i] * Wc2[i * 2 + 0];
            r1[i] = b2[i] * ws1[i] + bc1[i] * Wc2[i * 2 + 1];
            __syncthreads();
            for (int s = 128; s > 0; s >>= 1) {
                if (i < s) { r0[i] += r0[i + s]; r1[i] += r1[i + s]; }
                __syncthreads();
            }
            if (i == 0) { bbig[0] = r0[0] + bc2[0]; bbig[1] = r1[0] + bc2[1]; }
        }
    } else {
        int e = (bid - PREP_WB_END) * 256 + threadIdx.x;
        atomicAdd(&cnt[etype[e] * NNODES + edst[e]], 1);
    }
}

// ---------------------------------------------------------------------------
// 1024-thread two-level exclusive scan of cnt[65536] -> segstart[65537]
// ---------------------------------------------------------------------------
__global__ __launch_bounds__(1024) void k_scan(const int* __restrict__ cnt,
                                               int* __restrict__ segstart) {
    __shared__ int part[1024];
    __shared__ int sup[16];
    __shared__ int supx[16];
    int t = threadIdx.x;
    int base = t * 64;
    int s = 0;
    for (int i = 0; i < 64; i++) s += cnt[base + i];
    part[t] = s;
    __syncthreads();
    if (t < 16) {
        int a = 0;
        for (int i = 0; i < 64; i++) a += part[t * 64 + i];
        sup[t] = a;
    }
    __syncthreads();
    if (t == 0) {
        int a = 0;
        for (int i = 0; i < 16; i++) { supx[i] = a; a += sup[i]; }
    }
    __syncthreads();
    int a = supx[t >> 6];
    for (int i = (t & ~63); i < t; i++) a += part[i];
    for (int i = 0; i < 64; i++) { segstart[base + i] = a; a += cnt[base + i]; }
    if (t == 1023) segstart[NSEG] = a;
}

__global__ void k_scatter(const int* __restrict__ etype, const int* __restrict__ esrc,
                          const int* __restrict__ edst, const int* __restrict__ segstart,
                          int* __restrict__ cursor, int* __restrict__ esorted) {
    int e = blockIdx.x * 256 + threadIdx.x;
    if (e >= NEDGES) return;
    int key = etype[e] * NNODES + edst[e];
    int pos = atomicAdd(&cursor[key], 1);
    esorted[segstart[key] + pos] = esrc[e];
}

// ---------------------------------------------------------------------------
// Layer-1 aggregation (R8 measured form): one wave per (rel,dst) segment.
// ---------------------------------------------------------------------------
__global__ __launch_bounds__(256) void k_aggregate(
        const unsigned short* __restrict__ x, const int* __restrict__ segstart,
        const int* __restrict__ esorted, unsigned short* __restrict__ Xin) {
    int seg = blockIdx.x * 4 + (threadIdx.x >> 6);
    int lane = threadIdx.x & 63;
    int r = seg >> 13;
    int dstn = seg & (NNODES - 1);
    float a[8] = {0, 0, 0, 0, 0, 0, 0, 0};
    float b[8] = {0, 0, 0, 0, 0, 0, 0, 0};
    int s0 = segstart[seg], s1 = segstart[seg + 1];
    int t = s0;
    for (; t + 2 <= s1; t += 2) {
        uint4 v0 = *(const uint4*)(x + (size_t)esorted[t] * HIDD + lane * 8);
        uint4 v1 = *(const uint4*)(x + (size_t)esorted[t + 1] * HIDD + lane * 8);
        a[0] += b2f_lo(v0.x); a[1] += b2f_hi(v0.x);
        a[2] += b2f_lo(v0.y); a[3] += b2f_hi(v0.y);
        a[4] += b2f_lo(v0.z); a[5] += b2f_hi(v0.z);
        a[6] += b2f_lo(v0.w); a[7] += b2f_hi(v0.w);
        b[0] += b2f_lo(v1.x); b[1] += b2f_hi(v1.x);
        b[2] += b2f_lo(v1.y); b[3] += b2f_hi(v1.y);
        b[4] += b2f_lo(v1.z); b[5] += b2f_hi(v1.z);
        b[6] += b2f_lo(v1.w); b[7] += b2f_hi(v1.w);
    }
    if (t < s1) {
        uint4 v0 = *(const uint4*)(x + (size_t)esorted[t] * HIDD + lane * 8);
        a[0] += b2f_lo(v0.x); a[1] += b2f_hi(v0.x);
        a[2] += b2f_lo(v0.y); a[3] += b2f_hi(v0.y);
        a[4] += b2f_lo(v0.z); a[5] += b2f_hi(v0.z);
        a[6] += b2f_lo(v0.w); a[7] += b2f_hi(v0.w);
    }
    float iv = (s1 > s0) ? (1.0f / (float)(s1 - s0)) : 1.0f;
#pragma unroll
    for (int j = 0; j < 8; j++) a[j] = (a[j] + b[j]) * iv;
    uint4 u;
    u.x = (uint32_t)f2b(a[0]) | ((uint32_t)f2b(a[1]) << 16);
    u.y = (uint32_t)f2b(a[2]) | ((uint32_t)f2b(a[3]) << 16);
    u.z = (uint32_t)f2b(a[4]) | ((uint32_t)f2b(a[5]) << 16);
    u.w = (uint32_t)f2b(a[6]) | ((uint32_t)f2b(a[7]) << 16);
    *(uint4*)(Xin + (size_t)dstn * KSDIM + r * HIDD + lane * 8) = u;
}

// ---------------------------------------------------------------------------
// Layer-2 aggregate + graph-pool fused (R8 measured form, 2048 blocks).
// ---------------------------------------------------------------------------
__global__ __launch_bounds__(256) void k_aggpool(
        const unsigned short* __restrict__ x, const int* __restrict__ segstart,
        const int* __restrict__ esorted, float* __restrict__ PXp) {
    int b = blockIdx.x;
    int q = b & 3, r = (b >> 2) & 7, g = b >> 5;
    int wave = threadIdx.x >> 6, lane = threadIdx.x & 63;
    float a[8] = {0, 0, 0, 0, 0, 0, 0, 0};
    int segbase = r * NNODES + g * 128 + q * 32 + wave * 8;
#pragma unroll 1
    for (int i = 0; i < 8; ++i) {
        int s0 = segstart[segbase + i], s1 = segstart[segbase + i + 1];
        if (s0 == s1) continue;
        float p[8] = {0, 0, 0, 0, 0, 0, 0, 0};
        for (int t = s0; t < s1; ++t) {
            uint4 v = *(const uint4*)(x + (size_t)esorted[t] * HIDD + lane * 8);
            p[0] += b2f_lo(v.x); p[1] += b2f_hi(v.x);
            p[2] += b2f_lo(v.y); p[3] += b2f_hi(v.y);
            p[4] += b2f_lo(v.z); p[5] += b2f_hi(v.z);
            p[6] += b2f_lo(v.w); p[7] += b2f_hi(v.w);
        }
        float w = 1.0f / (128.0f * (float)(s1 - s0));
#pragma unroll
        for (int j = 0; j < 8; j++) a[j] += p[j] * w;
    }
    __shared__ float red[4][512];
#pragma unroll
    for (int j = 0; j < 8; j++) red[wave][lane * 8 + j] = a[j];
    __syncthreads();
    for (int c = threadIdx.x; c < 512; c += 256) {
        float s = red[0][c] + red[1][c] + red[2][c] + red[3][c];
        PXp[((size_t)q * 64 + g) * KSDIM + r * 512 + c] = s;
    }
}

// Root slice partials: PXp[q][g][4096+c] = (1/128) sum_{n in (g,q)} x2[n][c]
__global__ __launch_bounds__(256) void k_rootpool(
        const unsigned short* __restrict__ x, float* __restrict__ PXp) {
    int g = blockIdx.x >> 2, q = blockIdx.x & 3;
    int wave = threadIdx.x >> 6, lane = threadIdx.x & 63;
    float a[8] = {0, 0, 0, 0, 0, 0, 0, 0};
    int n0 = g * 128 + q * 32 + wave * 8;
#pragma unroll
    for (int i = 0; i < 8; ++i) {
        uint4 v = *(const uint4*)(x + (size_t)(n0 + i) * HIDD + lane * 8);
        a[0] += b2f_lo(v.x); a[1] += b2f_hi(v.x);
        a[2] += b2f_lo(v.y); a[3] += b2f_hi(v.y);
        a[4] += b2f_lo(v.z); a[5] += b2f_hi(v.z);
        a[6] += b2f_lo(v.w); a[7] += b2f_hi(v.w);
    }
    __shared__ float red[4][512];
#pragma unroll
    for (int j = 0; j < 8; j++) red[wave][lane * 8 + j] = a[j];
    __syncthreads();
    for (int c = threadIdx.x; c < 512; c += 256) {
        float s = red[0][c] + red[1][c] + red[2][c] + red[3][c];
        PXp[((size_t)q * 64 + g) * KSDIM + 4096 + c] = s * (1.0f / 128.0f);
    }
}

// ---------------------------------------------------------------------------
// bf16 MFMA GEMM, split-K partials. 256x128 tile, BK=64, 8 waves (4Mx2N),
// 64x64 wave tiles (acc[4][4]). TRIPLE-buffered LDS (144 KB, 1 block/CU),
// prefetch depth 2, COUNTED s_waitcnt vmcnt(6) — never 0 in the main loop
// (T4, the 8-phase template's essential lever). Race-safety: stage at iter t
// writes buf[(t+2)%3] == buf[(t-1)%3], whose ds_reads were all consumed by
// MFMAs (compiler lgkmcnt) before the iter-(t-1) trailing barrier; trailing
// vmcnt(6) leaves only the newest stage outstanding so buf[t+1] has landed.
// XOR swizzle slot = chunk ^ (row&7) (measured 0 conflicts). T5 setprio
// around the MFMA cluster.
// ---------------------------------------------------------------------------
__global__ __launch_bounds__(512, 2) void k_gemm(
        const unsigned short* __restrict__ A,   // [M][K] bf16
        const unsigned short* __restrict__ Bt,  // [N][K] bf16
        float* __restrict__ P,                  // [S][M][N] partials
        int M, int N, int K, int Kc) {
    __shared__ unsigned short As[3][256 * 64];  // 96 KB
    __shared__ unsigned short Bs[3][128 * 64];  // 48 KB
    const int tid = threadIdx.x;
    const int lane = tid & 63, wid = tid >> 6;
    const int tiles_m = M >> 8;
    const int tm = blockIdx.x % tiles_m, tn = blockIdx.x / tiles_m;
    const int m0 = tm << 8, n0 = tn << 7;
    const int wr = wid >> 1, wc = wid & 1;       // 4 (M) x 2 (N) wave grid
    const int k0 = blockIdx.y * Kc;

    f32x4 acc[4][4];
#pragma unroll
    for (int i = 0; i < 4; i++)
#pragma unroll
        for (int j = 0; j < 4; j++) acc[i][j] = (f32x4){0.f, 0.f, 0.f, 0.f};

    // staging: thread covers LDS rows rowg + i*64, slot tid&7; source chunk
    // inverse-swizzled (LDS slot s of row r holds global chunk s^(r&7)).
    const int rowg = tid >> 3;                   // 0..63
    const int srcc = (tid & 7) ^ (rowg & 7);
    const unsigned short* gA = A  + (size_t)(m0 + rowg) * K + k0 + srcc * 8;
    const unsigned short* gB = Bt + (size_t)(n0 + rowg) * K + k0 + srcc * 8;
    const int ldsbase = wid * 512;               // elems; +i*4096 per instr

    // 6 global_load_lds (wave-instructions) per stage: 4 for A, 2 for B.
    auto stage = [&](int bsel, int kt) {
#pragma unroll
        for (int i = 0; i < 4; ++i)
            __builtin_amdgcn_global_load_lds(
                (const __attribute__((address_space(1))) void*)(gA + kt + (size_t)i * 64 * K),
                (__attribute__((address_space(3))) void*)&As[bsel][i * 4096 + ldsbase], 16, 0, 0);
#pragma unroll
        for (int i = 0; i < 2; ++i)
            __builtin_amdgcn_global_load_lds(
                (const __attribute__((address_space(1))) void*)(gB + kt + (size_t)i * 64 * K),
                (__attribute__((address_space(3))) void*)&Bs[bsel][i * 4096 + ldsbase], 16, 0, 0);
    };

    const int arow = wr * 64 + (lane & 15);
    const int brow = wc * 64 + (lane & 15);
    const int l7 = lane & 7;
    const int c0 = lane >> 4;   // 0..3

    const int nt = Kc >> 6;
    // prologue: prefetch tiles 0 and 1
    stage(0, 0);
    if (nt > 1) {
        stage(1, 64);
        asm volatile("s_waitcnt vmcnt(6)" ::: "memory");   // tile 0 landed
    } else {
        asm volatile("s_waitcnt vmcnt(0)" ::: "memory");
    }
    __builtin_amdgcn_s_barrier();

    for (int t = 0; t < nt; ++t) {
        const int cur = t % 3;
        if (t + 2 < nt) stage((t + 2) % 3, (t + 2) * 64);
        __builtin_amdgcn_s_setprio(1);
#pragma unroll
        for (int s4 = 0; s4 < 2; ++s4) {
            const int slot = (c0 + s4 * 4) ^ l7;
            bf16x8 af[4], bfr[4];
#pragma unroll
            for (int m = 0; m < 4; m++)
                af[m] = *(const bf16x8*)&As[cur][(arow + m * 16) * 64 + slot * 8];
#pragma unroll
            for (int n = 0; n < 4; n++)
                bfr[n] = *(const bf16x8*)&Bs[cur][(brow + n * 16) * 64 + slot * 8];
#pragma unroll
            for (int m = 0; m < 4; m++)
#pragma unroll
                for (int n = 0; n < 4; n++)
                    acc[m][n] = __builtin_amdgcn_mfma_f32_16x16x32_bf16(af[m], bfr[n], acc[m][n], 0, 0, 0);
        }
        __builtin_amdgcn_s_setprio(0);
        if (t + 1 < nt) {
            if (t + 2 < nt)
                asm volatile("s_waitcnt vmcnt(6)" ::: "memory");  // tile t+1 landed
            else
                asm volatile("s_waitcnt vmcnt(0)" ::: "memory");  // final tile drain
            __builtin_amdgcn_s_barrier();
        }
    }

    float* Pout = P + (size_t)blockIdx.y * M * N;
    const int crow0 = m0 + wr * 64 + (lane >> 4) * 4;
    const int ccol0 = n0 + wc * 64 + (lane & 15);
#pragma unroll
    for (int n = 0; n < 4; n++) {
        int col = ccol0 + n * 16;
#pragma unroll
        for (int m = 0; m < 4; m++)
#pragma unroll
            for (int r = 0; r < 4; r++)
                Pout[(size_t)(crow0 + m * 16 + r) * N + col] = acc[m][n][r];
    }
}

// ---------------------------------------------------------------------------
// Reduce S=2 partials + bias (+ReLU) -> bf16 x (optionally + Xin root cols)
// ---------------------------------------------------------------------------
template <int RELU, int WROOT>
__global__ void k_reduce_bf(const float* __restrict__ P, const float* __restrict__ bias,
                            unsigned short* __restrict__ xbf, unsigned short* __restrict__ Xin,
                            int MN) {
    int idx = (blockIdx.x * 256 + threadIdx.x) * 4;
    f32x4 v = *(const f32x4*)&P[idx];
    v += *(const f32x4*)&P[(size_t)MN + idx];
    v += *(const f32x4*)&bias[idx & 511];
    if (RELU) {
#pragma unroll
        for (int j = 0; j < 4; j++) v[j] = fmaxf(v[j], 0.f);
    }
    us4 u = cvt4(v);
    *(us4*)&xbf[idx] = u;
    if (WROOT) {
        int row = idx >> 9, col = idx & 511;
        *(us4*)&Xin[(size_t)row * KSDIM + NRELS * HIDD + col] = u;
    }
}

// ---------------------------------------------------------------------------
// Final head: logits[g][t] = (sum_q PXp[q][g]) . Wbig[.][t] + bbig[t]; softmax.
// ---------------------------------------------------------------------------
__global__ void k_logits(const float* __restrict__ PXp, const float* __restrict__ Wbig,
                         const float* __restrict__ bbig, float* __restrict__ out) {
    __shared__ float r0[256], r1[256];
    int g = blockIdx.x, tid = threadIdx.x;
    const float* p0 = PXp + ((size_t)0 * 64 + g) * KSDIM;
    const float* p1 = PXp + ((size_t)1 * 64 + g) * KSDIM;
    const float* p2 = PXp + ((size_t)2 * 64 + g) * KSDIM;
    const float* p3 = PXp + ((size_t)3 * 64 + g) * KSDIM;
    float s0 = 0.f, s1 = 0.f;
#pragma unroll
    for (int i = 0; i < 18; i++) {
        int k = i * 256 + tid;
        float px = p0[k] + p1[k] + p2[k] + p3[k];
        s0 += px * Wbig[k * 2 + 0];
        s1 += px * Wbig[k * 2 + 1];
    }
    r0[tid] = s0; r1[tid] = s1;
    __syncthreads();
    for (int s = 128; s > 0; s >>= 1) {
        if (tid < s) { r0[tid] += r0[tid + s]; r1[tid] += r1[tid + s]; }
        __syncthreads();
    }
    if (tid == 0) {
        float l0 = r0[0] + bbig[0], l1 = r1[0] + bbig[1];
        out[g * 2 + 0] = l0;
        out[g * 2 + 1] = l1;
        float m = fmaxf(l0, l1);
        float e0 = expf(l0 - m), e1 = expf(l1 - m);
        float inv = 1.0f / (e0 + e1);
        out[128 + g * 2 + 0] = e0 * inv;
        out[128 + g * 2 + 1] = e1 * inv;
    }
}

// ---------------------------------------------------------------------------
extern "C" void kernel_launch(void* const* d_in, const int* in_sizes, int n_in,
                              void* d_out, int out_size, void* d_ws, size_t ws_size,
                              hipStream_t stream) {
    const float* box     = (const float*)d_in[0];
    const int*   labels  = (const int*)d_in[1];
    const int*   eidx    = (const int*)d_in[2];
    const int*   etype   = (const int*)d_in[3];
    const float* emb     = (const float*)d_in[5];
    const float* W_lin   = (const float*)d_in[6];
    const float* b_lin   = (const float*)d_in[7];
    const float* rel_W1  = (const float*)d_in[8];
    const float* root_W1 = (const float*)d_in[9];
    const float* b1      = (const float*)d_in[10];
    const float* rel_W2  = (const float*)d_in[11];
    const float* root_W2 = (const float*)d_in[12];
    const float* b2      = (const float*)d_in[13];
    const float* Wc1     = (const float*)d_in[14];
    const float* bc1     = (const float*)d_in[15];
    const float* Wc2     = (const float*)d_in[16];
    const float* bc2     = (const float*)d_in[17];
    const int* esrc = eidx;
    const int* edst = eidx + NEDGES;

    char* ws = (char*)d_ws;
    size_t off = 0;
    auto alloc = [&](size_t bytes) -> char* {
        char* p = ws + off;
        off += (bytes + 255) & ~(size_t)255;
        return p;
    };
    float* Pp = (float*)alloc((size_t)2 * NNODES * HIDD * 4);   // 32 MB, S=2
    unsigned short* Xin = (unsigned short*)alloc((size_t)NNODES * KSDIM * 2);  // 75.5 MB
    unsigned short* X0  = Xin;   // packed [8192][1280]; dead after L0 GEMM
    unsigned short* xbf = (unsigned short*)alloc((size_t)NNODES * HIDD * 2);
    unsigned short* W0t = (unsigned short*)alloc((size_t)HIDD * K0DIM * 2);
    unsigned short* W1t = (unsigned short*)alloc((size_t)HIDD * KSDIM * 2);
    float* PXp    = (float*)alloc((size_t)4 * 64 * KSDIM * 4);  // 4.7 MB
    float* Wbig   = (float*)alloc((size_t)KSDIM * 2 * 4);
    float* bbig   = (float*)alloc(2 * 4);
    int*   cnt     = (int*)alloc((size_t)NSEG * 4);
    int*   cursor  = (int*)alloc((size_t)NSEG * 4);   // contiguous with cnt
    int*   segst   = (int*)alloc((size_t)(NSEG + 1) * 4);
    int*   esorted = (int*)alloc((size_t)NEDGES * 4);
    if (off > ws_size) return;

    float* out = (float*)d_out;
    const int MN = NNODES * HIDD;

    // --- prep: memset + fused {build_x0 | transposes | head-fold | hist} ---
    hipMemsetAsync(cnt, 0, (size_t)2 * NSEG * 4, stream);   // cnt + cursor
    k_prep<<<PREP_TOTAL, 256, 0, stream>>>(
        box, labels, emb, W_lin, rel_W1, root_W1, rel_W2, root_W2,
        Wc1, bc1, Wc2, bc2, b2, etype, edst,
        X0, W0t, W1t, Wbig, bbig, cnt);
    k_scan<<<1, 1024, 0, stream>>>(cnt, segst);
    k_scatter<<<NEDGES / 256, 256, 0, stream>>>(etype, esrc, edst, segst, cursor, esorted);

    // --- layer 0: x1 = X0 @ W_lin + b_lin  (S=2, Kc=640; 256x128 tiles) ---
    k_gemm<<<dim3((NNODES / 256) * (HIDD / 128), 2), 512, 0, stream>>>(
        X0, W0t, Pp, NNODES, HIDD, K0DIM, K0DIM / 2);
    k_reduce_bf<0, 1><<<MN / 1024, 256, 0, stream>>>(Pp, b_lin, xbf, Xin, MN);

    // --- RGCN layer 1: x2 = relu([A(x1) | x1] @ [rel_W1; root_W1] + b1)  (S=2) ---
    k_aggregate<<<NSEG / 4, 256, 0, stream>>>(xbf, segst, esorted, Xin);
    k_gemm<<<dim3((NNODES / 256) * (HIDD / 128), 2), 512, 0, stream>>>(
        Xin, W1t, Pp, NNODES, HIDD, KSDIM, KSDIM / 2);
    k_reduce_bf<1, 0><<<MN / 1024, 256, 0, stream>>>(Pp, b1, xbf, Xin, MN);

    // --- layer 2 + pool + classifier, fully folded ---
    k_aggpool<<<2048, 256, 0, stream>>>(xbf, segst, esorted, PXp);
    k_rootpool<<<256, 256, 0, stream>>>(xbf, PXp);
    k_logits<<<64, 256, 0, stream>>>(PXp, Wbig, bbig, out);
}

// Round 15
// 246.252 us; speedup vs baseline: 1.1079x; 1.0449x over previous
//
#include <hip/hip_runtime.h>
#include <cstdint>

#define NNODES 8192
#define NEDGES 262144
#define NRELS  8
#define EMBD   256
#define BOXD   1024
#define HIDD   512
#define OUTD   256
#define NSEG   (NRELS * NNODES)      // 65536
#define K0DIM  (BOXD + EMBD)         // 1280
#define KSDIM  (NRELS * HIDD + HIDD) // 4608

// k_prep block-range boundaries
#define PREP_X0_END   8192
#define PREP_TR_END   (8192 + 2944)
#define PREP_WB_END   (8192 + 2944 + 18)
#define PREP_TOTAL    (8192 + 2944 + 18 + 1024)

using bf16x8 = __attribute__((ext_vector_type(8))) short;
using f32x4  = __attribute__((ext_vector_type(4))) float;
using us4    = __attribute__((ext_vector_type(4))) unsigned short;

__device__ __forceinline__ unsigned short f2b(float f) {
    union { float f; uint32_t u; } v; v.f = f;
    uint32_t r = v.u + 0x7FFFu + ((v.u >> 16) & 1u);
    return (unsigned short)(r >> 16);
}

__device__ __forceinline__ us4 cvt4(f32x4 v) {
    us4 u;
    u[0] = f2b(v[0]); u[1] = f2b(v[1]); u[2] = f2b(v[2]); u[3] = f2b(v[3]);
    return u;
}

__device__ __forceinline__ float b2f_lo(uint32_t w) {
    union { uint32_t u; float f; } v; v.u = w << 16; return v.f;
}
__device__ __forceinline__ float b2f_hi(uint32_t w) {
    union { uint32_t u; float f; } v; v.u = w & 0xffff0000u; return v.f;
}

// ---------------------------------------------------------------------------
// Fused prep: build_x0 | weight transposes | head-weight fold | edge histogram.
// ---------------------------------------------------------------------------
__global__ __launch_bounds__(256) void k_prep(
        const float* __restrict__ box, const int* __restrict__ labels,
        const float* __restrict__ emb,
        const float* __restrict__ W_lin, const float* __restrict__ rel_W1,
        const float* __restrict__ root_W1, const float* __restrict__ rel_W2,
        const float* __restrict__ root_W2,
        const float* __restrict__ Wc1, const float* __restrict__ bc1,
        const float* __restrict__ Wc2, const float* __restrict__ bc2,
        const float* __restrict__ b2,
        const int* __restrict__ etype, const int* __restrict__ edst,
        unsigned short* __restrict__ X0, unsigned short* __restrict__ W0t,
        unsigned short* __restrict__ W1t, float* __restrict__ Wbig,
        float* __restrict__ bbig, int* __restrict__ cnt) {
    int bid = blockIdx.x;
    if (bid < PREP_X0_END) {
        int n = bid;
        int lab = labels[n];
        const f32x4* b = (const f32x4*)(box + (size_t)n * BOXD);
        const f32x4* e = (const f32x4*)(emb + (size_t)lab * EMBD);
        us4* o = (us4*)(X0 + (size_t)n * K0DIM);
        for (int j = threadIdx.x; j < K0DIM / 4; j += 256) {
            f32x4 v = (j < BOXD / 4) ? b[j] : e[j - BOXD / 4];
            o[j] = cvt4(v);
        }
    } else if (bid < PREP_TR_END) {
        __shared__ float t[32][33];
        int lb = bid - PREP_X0_END;
        const float* src; unsigned short* dst; int No, ld, kOff, kb, ob;
        if (lb < 640)       { int g = lb;        src = W_lin;   dst = W0t; No = 512; ld = K0DIM; kOff = 0;    kb = g % 40;  ob = g / 40; }
        else if (lb < 2688) { int g = lb - 640;  src = rel_W1;  dst = W1t; No = 512; ld = KSDIM; kOff = 0;    kb = g % 128; ob = g / 128; }
        else                { int g = lb - 2688; src = root_W1; dst = W1t; No = 512; ld = KSDIM; kOff = 4096; kb = g % 16;  ob = g / 16; }
        int kt = kb * 32, ot = ob * 32;
        int tx = threadIdx.x & 31, ty = threadIdx.x >> 5; // 32 x 8
#pragma unroll
        for (int i = 0; i < 4; i++) {
            int k = kt + ty + i * 8;
            t[ty + i * 8][tx] = src[(size_t)k * No + ot + tx];
        }
        __syncthreads();
#pragma unroll
        for (int i = 0; i < 4; i++) {
            int o = ot + ty + i * 8;
            dst[(size_t)o * ld + kOff + kt + tx] = f2b(t[tx][ty + i * 8]);
        }
    } else if (bid < PREP_WB_END) {
        __shared__ float ws0[256], ws1[256];
        __shared__ float r0[256], r1[256];
        int g = bid - PREP_TR_END;   // 0..17
        int i = threadIdx.x;
        float w0 = 0.f, w1 = 0.f;
        for (int o = 0; o < 256; o++) {
            float c = Wc1[i * 256 + o];
            w0 += c * Wc2[o * 2 + 0];
            w1 += c * Wc2[o * 2 + 1];
        }
        ws0[i] = w0; ws1[i] = w1;
        __syncthreads();
        int k = g * 256 + i;
        const float* row = (k < 4096) ? rel_W2 + (size_t)k * 256
                                      : root_W2 + (size_t)(k - 4096) * 256;
        float s0 = 0.f, s1 = 0.f;
        for (int o = 0; o < 256; o++) {
            float v = row[o];
            s0 += v * ws0[o];
            s1 += v * ws1[o];
        }
        Wbig[k * 2 + 0] = s0;
        Wbig[k * 2 + 1] = s1;
        if (g == 0) {
            r0[i] = b2[i] * ws0[i] + bc1[i] * Wc2[i * 2 + 0];
            r1[i] = b2[i] * ws1[i] + bc1[i] * Wc2[i * 2 + 1];
            __syncthreads();
            for (int s = 128; s > 0; s >>= 1) {
                if (i < s) { r0[i] += r0[i + s]; r1[i] += r1[i + s]; }
                __syncthreads();
            }
            if (i == 0) { bbig[0] = r0[0] + bc2[0]; bbig[1] = r1[0] + bc2[1]; }
        }
    } else {
        int e = (bid - PREP_WB_END) * 256 + threadIdx.x;
        atomicAdd(&cnt[etype[e] * NNODES + edst[e]], 1);
    }
}

// ---------------------------------------------------------------------------
// 1024-thread two-level exclusive scan of cnt[65536] -> segstart[65537]
// ---------------------------------------------------------------------------
__global__ __launch_bounds__(1024) void k_scan(const int* __restrict__ cnt,
                                               int* __restrict__ segstart) {
    __shared__ int part[1024];
    __shared__ int sup[16];
    __shared__ int supx[16];
    int t = threadIdx.x;
    int base = t * 64;
    int s = 0;
    for (int i = 0; i < 64; i++) s += cnt[base + i];
    part[t] = s;
    __syncthreads();
    if (t < 16) {
        int a = 0;
        for (int i = 0; i < 64; i++) a += part[t * 64 + i];
        sup[t] = a;
    }
    __syncthreads();
    if (t == 0) {
        int a = 0;
        for (int i = 0; i < 16; i++) { supx[i] = a; a += sup[i]; }
    }
    __syncthreads();
    int a = supx[t >> 6];
    for (int i = (t & ~63); i < t; i++) a += part[i];
    for (int i = 0; i < 64; i++) { segstart[base + i] = a; a += cnt[base + i]; }
    if (t == 1023) segstart[NSEG] = a;
}

__global__ void k_scatter(const int* __restrict__ etype, const int* __restrict__ esrc,
                          const int* __restrict__ edst, const int* __restrict__ segstart,
                          int* __restrict__ cursor, int* __restrict__ esorted) {
    int e = blockIdx.x * 256 + threadIdx.x;
    if (e >= NEDGES) return;
    int key = etype[e] * NNODES + edst[e];
    int pos = atomicAdd(&cursor[key], 1);
    esorted[segstart[key] + pos] = esrc[e];
}

// ---------------------------------------------------------------------------
// Layer-1 aggregation (R8 measured form): one wave per (rel,dst) segment.
// ---------------------------------------------------------------------------
__global__ __launch_bounds__(256) void k_aggregate(
        const unsigned short* __restrict__ x, const int* __restrict__ segstart,
        const int* __restrict__ esorted, unsigned short* __restrict__ Xin) {
    int seg = blockIdx.x * 4 + (threadIdx.x >> 6);
    int lane = threadIdx.x & 63;
    int r = seg >> 13;
    int dstn = seg & (NNODES - 1);
    float a[8] = {0, 0, 0, 0, 0, 0, 0, 0};
    float b[8] = {0, 0, 0, 0, 0, 0, 0, 0};
    int s0 = segstart[seg], s1 = segstart[seg + 1];
    int t = s0;
    for (; t + 2 <= s1; t += 2) {
        uint4 v0 = *(const uint4*)(x + (size_t)esorted[t] * HIDD + lane * 8);
        uint4 v1 = *(const uint4*)(x + (size_t)esorted[t + 1] * HIDD + lane * 8);
        a[0] += b2f_lo(v0.x); a[1] += b2f_hi(v0.x);
        a[2] += b2f_lo(v0.y); a[3] += b2f_hi(v0.y);
        a[4] += b2f_lo(v0.z); a[5] += b2f_hi(v0.z);
        a[6] += b2f_lo(v0.w); a[7] += b2f_hi(v0.w);
        b[0] += b2f_lo(v1.x); b[1] += b2f_hi(v1.x);
        b[2] += b2f_lo(v1.y); b[3] += b2f_hi(v1.y);
        b[4] += b2f_lo(v1.z); b[5] += b2f_hi(v1.z);
        b[6] += b2f_lo(v1.w); b[7] += b2f_hi(v1.w);
    }
    if (t < s1) {
        uint4 v0 = *(const uint4*)(x + (size_t)esorted[t] * HIDD + lane * 8);
        a[0] += b2f_lo(v0.x); a[1] += b2f_hi(v0.x);
        a[2] += b2f_lo(v0.y); a[3] += b2f_hi(v0.y);
        a[4] += b2f_lo(v0.z); a[5] += b2f_hi(v0.z);
        a[6] += b2f_lo(v0.w); a[7] += b2f_hi(v0.w);
    }
    float iv = (s1 > s0) ? (1.0f / (float)(s1 - s0)) : 1.0f;
#pragma unroll
    for (int j = 0; j < 8; j++) a[j] = (a[j] + b[j]) * iv;
    uint4 u;
    u.x = (uint32_t)f2b(a[0]) | ((uint32_t)f2b(a[1]) << 16);
    u.y = (uint32_t)f2b(a[2]) | ((uint32_t)f2b(a[3]) << 16);
    u.z = (uint32_t)f2b(a[4]) | ((uint32_t)f2b(a[5]) << 16);
    u.w = (uint32_t)f2b(a[6]) | ((uint32_t)f2b(a[7]) << 16);
    *(uint4*)(Xin + (size_t)dstn * KSDIM + r * HIDD + lane * 8) = u;
}

// ---------------------------------------------------------------------------
// Layer-2 aggregate + graph-pool fused (R8 measured form, 2048 blocks).
// Kept SEPARATE from rootpool: the merged 2304-block variant measured +7us
// slower in R11.
// ---------------------------------------------------------------------------
__global__ __launch_bounds__(256) void k_aggpool(
        const unsigned short* __restrict__ x, const int* __restrict__ segstart,
        const int* __restrict__ esorted, float* __restrict__ PXp) {
    int b = blockIdx.x;
    int q = b & 3, r = (b >> 2) & 7, g = b >> 5;
    int wave = threadIdx.x >> 6, lane = threadIdx.x & 63;
    float a[8] = {0, 0, 0, 0, 0, 0, 0, 0};
    int segbase = r * NNODES + g * 128 + q * 32 + wave * 8;
#pragma unroll 1
    for (int i = 0; i < 8; ++i) {
        int s0 = segstart[segbase + i], s1 = segstart[segbase + i + 1];
        if (s0 == s1) continue;
        float p[8] = {0, 0, 0, 0, 0, 0, 0, 0};
        for (int t = s0; t < s1; ++t) {
            uint4 v = *(const uint4*)(x + (size_t)esorted[t] * HIDD + lane * 8);
            p[0] += b2f_lo(v.x); p[1] += b2f_hi(v.x);
            p[2] += b2f_lo(v.y); p[3] += b2f_hi(v.y);
            p[4] += b2f_lo(v.z); p[5] += b2f_hi(v.z);
            p[6] += b2f_lo(v.w); p[7] += b2f_hi(v.w);
        }
        float w = 1.0f / (128.0f * (float)(s1 - s0));
#pragma unroll
        for (int j = 0; j < 8; j++) a[j] += p[j] * w;
    }
    __shared__ float red[4][512];
#pragma unroll
    for (int j = 0; j < 8; j++) red[wave][lane * 8 + j] = a[j];
    __syncthreads();
    for (int c = threadIdx.x; c < 512; c += 256) {
        float s = red[0][c] + red[1][c] + red[2][c] + red[3][c];
        PXp[((size_t)q * 64 + g) * KSDIM + r * 512 + c] = s;
    }
}

// Root slice partials: PXp[q][g][4096+c] = (1/128) sum_{n in (g,q)} x2[n][c]
__global__ __launch_bounds__(256) void k_rootpool(
        const unsigned short* __restrict__ x, float* __restrict__ PXp) {
    int g = blockIdx.x >> 2, q = blockIdx.x & 3;
    int wave = threadIdx.x >> 6, lane = threadIdx.x & 63;
    float a[8] = {0, 0, 0, 0, 0, 0, 0, 0};
    int n0 = g * 128 + q * 32 + wave * 8;
#pragma unroll
    for (int i = 0; i < 8; ++i) {
        uint4 v = *(const uint4*)(x + (size_t)(n0 + i) * HIDD + lane * 8);
        a[0] += b2f_lo(v.x); a[1] += b2f_hi(v.x);
        a[2] += b2f_lo(v.y); a[3] += b2f_hi(v.y);
        a[4] += b2f_lo(v.z); a[5] += b2f_hi(v.z);
        a[6] += b2f_lo(v.w); a[7] += b2f_hi(v.w);
    }
    __shared__ float red[4][512];
#pragma unroll
    for (int j = 0; j < 8; j++) red[wave][lane * 8 + j] = a[j];
    __syncthreads();
    for (int c = threadIdx.x; c < 512; c += 256) {
        float s = red[0][c] + red[1][c] + red[2][c] + red[3][c];
        PXp[((size_t)q * 64 + g) * KSDIM + 4096 + c] = s * (1.0f / 128.0f);
    }
}

// ---------------------------------------------------------------------------
// bf16 MFMA GEMM, split-K partials. 128x128 tile, BK=64, 8 waves (2x4),
// LDS [128][64]/buffer, XOR swizzle slot = chunk ^ (row&7), double-buffered,
// one vmcnt(0)+barrier drain per K-tile.
// EMPIRICAL OPTIMUM of 5 tried configs (R2/R3/R4/R9/R14): 47.7us, MfmaUtil
// 32%, 2 blocks/CU. R9/R14 proved the loss at 256x128 is occupancy (1 blk/CU,
// 8 waves), NOT the barrier drain — counted-vmcnt triple-buffer gave 0 gain.
// Do not trade blocks/CU for anything at this structure.
// ---------------------------------------------------------------------------
__global__ __launch_bounds__(512, 4) void k_gemm(
        const unsigned short* __restrict__ A,   // [M][K] bf16
        const unsigned short* __restrict__ Bt,  // [N][K] bf16
        float* __restrict__ P,                  // [S][M][N] partials
        int M, int N, int K, int Kc) {
    __shared__ unsigned short As[2][128 * 64];
    __shared__ unsigned short Bs[2][128 * 64];
    const int tid = threadIdx.x;
    const int lane = tid & 63, wid = tid >> 6;
    const int tiles_m = M >> 7;
    const int tm = blockIdx.x % tiles_m, tn = blockIdx.x / tiles_m;
    const int m0 = tm << 7, n0 = tn << 7;
    const int wr = wid >> 2, wc = wid & 3;       // 2 x 4 wave grid
    const int k0 = blockIdx.y * Kc;

    f32x4 acc[4][2];
#pragma unroll
    for (int i = 0; i < 4; i++)
#pragma unroll
        for (int j = 0; j < 2; j++) acc[i][j] = (f32x4){0.f, 0.f, 0.f, 0.f};

    const int rowg = tid >> 3;
    const int srcc = (tid & 7) ^ (rowg & 7);
    const unsigned short* gA = A  + (size_t)(m0 + rowg) * K + k0 + srcc * 8;
    const unsigned short* gB = Bt + (size_t)(n0 + rowg) * K + k0 + srcc * 8;
    const int ldsbase = wid * 512;

    auto stage = [&](int bsel, int kt) {
#pragma unroll
        for (int i = 0; i < 2; ++i) {
            __builtin_amdgcn_global_load_lds(
                (const __attribute__((address_space(1))) void*)(gA + kt + i * 64 * K),
                (__attribute__((address_space(3))) void*)&As[bsel][i * 4096 + ldsbase], 16, 0, 0);
            __builtin_amdgcn_global_load_lds(
                (const __attribute__((address_space(1))) void*)(gB + kt + i * 64 * K),
                (__attribute__((address_space(3))) void*)&Bs[bsel][i * 4096 + ldsbase], 16, 0, 0);
        }
    };

    const int arow = wr * 64 + (lane & 15);
    const int brow = wc * 32 + (lane & 15);
    const int l7 = lane & 7;
    const int c0 = lane >> 4;   // 0..3

    const int nt = Kc >> 6;
    int cur = 0;
    stage(0, 0);
    asm volatile("s_waitcnt vmcnt(0)" ::: "memory");
    __builtin_amdgcn_s_barrier();

    for (int t = 0; t < nt; ++t) {
        if (t + 1 < nt) stage(cur ^ 1, (t + 1) * 64);
#pragma unroll
        for (int s4 = 0; s4 < 2; ++s4) {
            const int slot = (c0 + s4 * 4) ^ l7;
            bf16x8 af[4], bfr[2];
#pragma unroll
            for (int m = 0; m < 4; m++)
                af[m] = *(const bf16x8*)&As[cur][(arow + m * 16) * 64 + slot * 8];
#pragma unroll
            for (int n = 0; n < 2; n++)
                bfr[n] = *(const bf16x8*)&Bs[cur][(brow + n * 16) * 64 + slot * 8];
#pragma unroll
            for (int m = 0; m < 4; m++)
#pragma unroll
                for (int n = 0; n < 2; n++)
                    acc[m][n] = __builtin_amdgcn_mfma_f32_16x16x32_bf16(af[m], bfr[n], acc[m][n], 0, 0, 0);
        }
        if (t + 1 < nt) {
            asm volatile("s_waitcnt vmcnt(0)" ::: "memory");
            __builtin_amdgcn_s_barrier();
            cur ^= 1;
        }
    }

    float* Pout = P + (size_t)blockIdx.y * M * N;
    const int crow0 = m0 + wr * 64 + (lane >> 4) * 4;
    const int ccol0 = n0 + wc * 32 + (lane & 15);
#pragma unroll
    for (int n = 0; n < 2; n++) {
        int col = ccol0 + n * 16;
#pragma unroll
        for (int m = 0; m < 4; m++)
#pragma unroll
            for (int r = 0; r < 4; r++)
                Pout[(size_t)(crow0 + m * 16 + r) * N + col] = acc[m][n][r];
    }
}

// ---------------------------------------------------------------------------
// Reduce S=2 partials + bias (+ReLU) -> bf16 x (optionally + Xin root cols)
// ---------------------------------------------------------------------------
template <int RELU, int WROOT>
__global__ void k_reduce_bf(const float* __restrict__ P, const float* __restrict__ bias,
                            unsigned short* __restrict__ xbf, unsigned short* __restrict__ Xin,
                            int MN) {
    int idx = (blockIdx.x * 256 + threadIdx.x) * 4;
    f32x4 v = *(const f32x4*)&P[idx];
    v += *(const f32x4*)&P[(size_t)MN + idx];
    v += *(const f32x4*)&bias[idx & 511];
    if (RELU) {
#pragma unroll
        for (int j = 0; j < 4; j++) v[j] = fmaxf(v[j], 0.f);
    }
    us4 u = cvt4(v);
    *(us4*)&xbf[idx] = u;
    if (WROOT) {
        int row = idx >> 9, col = idx & 511;
        *(us4*)&Xin[(size_t)row * KSDIM + NRELS * HIDD + col] = u;
    }
}

// ---------------------------------------------------------------------------
// Final head: logits[g][t] = (sum_q PXp[q][g]) . Wbig[.][t] + bbig[t]; softmax.
// ---------------------------------------------------------------------------
__global__ void k_logits(const float* __restrict__ PXp, const float* __restrict__ Wbig,
                         const float* __restrict__ bbig, float* __restrict__ out) {
    __shared__ float r0[256], r1[256];
    int g = blockIdx.x, tid = threadIdx.x;
    const float* p0 = PXp + ((size_t)0 * 64 + g) * KSDIM;
    const float* p1 = PXp + ((size_t)1 * 64 + g) * KSDIM;
    const float* p2 = PXp + ((size_t)2 * 64 + g) * KSDIM;
    const float* p3 = PXp + ((size_t)3 * 64 + g) * KSDIM;
    float s0 = 0.f, s1 = 0.f;
#pragma unroll
    for (int i = 0; i < 18; i++) {
        int k = i * 256 + tid;
        float px = p0[k] + p1[k] + p2[k] + p3[k];
        s0 += px * Wbig[k * 2 + 0];
        s1 += px * Wbig[k * 2 + 1];
    }
    r0[tid] = s0; r1[tid] = s1;
    __syncthreads();
    for (int s = 128; s > 0; s >>= 1) {
        if (tid < s) { r0[tid] += r0[tid + s]; r1[tid] += r1[tid + s]; }
        __syncthreads();
    }
    if (tid == 0) {
        float l0 = r0[0] + bbig[0], l1 = r1[0] + bbig[1];
        out[g * 2 + 0] = l0;
        out[g * 2 + 1] = l1;
        float m = fmaxf(l0, l1);
        float e0 = expf(l0 - m), e1 = expf(l1 - m);
        float inv = 1.0f / (e0 + e1);
        out[128 + g * 2 + 0] = e0 * inv;
        out[128 + g * 2 + 1] = e1 * inv;
    }
}

// ---------------------------------------------------------------------------
extern "C" void kernel_launch(void* const* d_in, const int* in_sizes, int n_in,
                              void* d_out, int out_size, void* d_ws, size_t ws_size,
                              hipStream_t stream) {
    const float* box     = (const float*)d_in[0];
    const int*   labels  = (const int*)d_in[1];
    const int*   eidx    = (const int*)d_in[2];
    const int*   etype   = (const int*)d_in[3];
    const float* emb     = (const float*)d_in[5];
    const float* W_lin   = (const float*)d_in[6];
    const float* b_lin   = (const float*)d_in[7];
    const float* rel_W1  = (const float*)d_in[8];
    const float* root_W1 = (const float*)d_in[9];
    const float* b1      = (const float*)d_in[10];
    const float* rel_W2  = (const float*)d_in[11];
    const float* root_W2 = (const float*)d_in[12];
    const float* b2      = (const float*)d_in[13];
    const float* Wc1     = (const float*)d_in[14];
    const float* bc1     = (const float*)d_in[15];
    const float* Wc2     = (const float*)d_in[16];
    const float* bc2     = (const float*)d_in[17];
    const int* esrc = eidx;
    const int* edst = eidx + NEDGES;

    char* ws = (char*)d_ws;
    size_t off = 0;
    auto alloc = [&](size_t bytes) -> char* {
        char* p = ws + off;
        off += (bytes + 255) & ~(size_t)255;
        return p;
    };
    float* Pp = (float*)alloc((size_t)2 * NNODES * HIDD * 4);   // 32 MB, S=2
    unsigned short* Xin = (unsigned short*)alloc((size_t)NNODES * KSDIM * 2);  // 75.5 MB
    unsigned short* X0  = Xin;   // packed [8192][1280]; dead after L0 GEMM
    unsigned short* xbf = (unsigned short*)alloc((size_t)NNODES * HIDD * 2);
    unsigned short* W0t = (unsigned short*)alloc((size_t)HIDD * K0DIM * 2);
    unsigned short* W1t = (unsigned short*)alloc((size_t)HIDD * KSDIM * 2);
    float* PXp    = (float*)alloc((size_t)4 * 64 * KSDIM * 4);  // 4.7 MB
    float* Wbig   = (float*)alloc((size_t)KSDIM * 2 * 4);
    float* bbig   = (float*)alloc(2 * 4);
    int*   cnt     = (int*)alloc((size_t)NSEG * 4);
    int*   cursor  = (int*)alloc((size_t)NSEG * 4);   // contiguous with cnt
    int*   segst   = (int*)alloc((size_t)(NSEG + 1) * 4);
    int*   esorted = (int*)alloc((size_t)NEDGES * 4);
    if (off > ws_size) return;

    float* out = (float*)d_out;
    const int MN = NNODES * HIDD;

    // --- prep: memset + fused {build_x0 | transposes | head-fold | hist} ---
    hipMemsetAsync(cnt, 0, (size_t)2 * NSEG * 4, stream);   // cnt + cursor
    k_prep<<<PREP_TOTAL, 256, 0, stream>>>(
        box, labels, emb, W_lin, rel_W1, root_W1, rel_W2, root_W2,
        Wc1, bc1, Wc2, bc2, b2, etype, edst,
        X0, W0t, W1t, Wbig, bbig, cnt);
    k_scan<<<1, 1024, 0, stream>>>(cnt, segst);
    k_scatter<<<NEDGES / 256, 256, 0, stream>>>(etype, esrc, edst, segst, cursor, esorted);

    // --- layer 0: x1 = X0 @ W_lin + b_lin  (S=2, Kc=640; 128x128 tiles) ---
    k_gemm<<<dim3((NNODES / 128) * (HIDD / 128), 2), 512, 0, stream>>>(
        X0, W0t, Pp, NNODES, HIDD, K0DIM, K0DIM / 2);
    k_reduce_bf<0, 1><<<MN / 1024, 256, 0, stream>>>(Pp, b_lin, xbf, Xin, MN);

    // --- RGCN layer 1: x2 = relu([A(x1) | x1] @ [rel_W1; root_W1] + b1)  (S=2) ---
    k_aggregate<<<NSEG / 4, 256, 0, stream>>>(xbf, segst, esorted, Xin);
    k_gemm<<<dim3((NNODES / 128) * (HIDD / 128), 2), 512, 0, stream>>>(
        Xin, W1t, Pp, NNODES, HIDD, KSDIM, KSDIM / 2);
    k_reduce_bf<1, 0><<<MN / 1024, 256, 0, stream>>>(Pp, b1, xbf, Xin, MN);

    // --- layer 2 + pool + classifier, fully folded ---
    k_aggpool<<<2048, 256, 0, stream>>>(xbf, segst, esorted, PXp);
    k_rootpool<<<256, 256, 0, stream>>>(xbf, PXp);
    k_logits<<<64, 256, 0, stream>>>(PXp, Wbig, bbig, out);
}